// Round 1
// baseline (255.134 us; speedup 1.0000x reference)
//
#include <hip/hip_runtime.h>
#include <hip/hip_bf16.h>

#define BB 2
#define SS 2048
#define EE 1024
#define HH 16
#define DD 64
#define MM (BB*SS)      // 4096
#define N1 (3*EE)       // 3072

typedef __attribute__((ext_vector_type(4))) float f32x4;
typedef __attribute__((ext_vector_type(8))) short bf16x8;

__device__ __forceinline__ ushort f2bf(float f){
  union { float f; unsigned u; } v; v.f = f;
  unsigned r = v.u + 0x7fffu + ((v.u >> 16) & 1u);
  return (ushort)(r >> 16);
}

// ---- fp32 -> bf16 straight convert (vectorized x4) ----
__global__ void cvt_kernel(const float* __restrict__ in, ushort* __restrict__ out, int n4){
  int i = blockIdx.x*blockDim.x + threadIdx.x;
  if (i < n4){
    const float4 f = reinterpret_cast<const float4*>(in)[i];
    ushort4 o;
    o.x = f2bf(f.x); o.y = f2bf(f.y); o.z = f2bf(f.z); o.w = f2bf(f.w);
    reinterpret_cast<ushort4*>(out)[i] = o;
  }
}

// ---- fp32 [K,N] -> bf16 [N,K] transposed convert, 32x32 LDS tiles ----
__global__ void cvtT_kernel(const float* __restrict__ in, ushort* __restrict__ out, int K, int N){
  __shared__ float t[32][33];
  int n0 = blockIdx.x*32, k0 = blockIdx.y*32;
  int tx = threadIdx.x, ty = threadIdx.y;
  for (int r = ty; r < 32; r += 8)
    t[r][tx] = in[(size_t)(k0+r)*N + n0 + tx];
  __syncthreads();
  for (int r = ty; r < 32; r += 8)
    out[(size_t)(n0+r)*K + k0 + tx] = f2bf(t[tx][r]);
}

// ---- bf16 GEMM: C[M,N] = A[M,K] * Bt[N,K]^T + bias. 128x128 tile, BK=32 ----
template<int BF16_OUT>
__global__ __launch_bounds__(256) void gemm_nt(const ushort* __restrict__ A,
    const ushort* __restrict__ Bt, const float* __restrict__ bias,
    ushort* __restrict__ ob, float* __restrict__ of, int M, int N, int K){
  __shared__ ushort As[128][40];
  __shared__ ushort Bs[128][40];
  int tid = threadIdx.x;
  int lane = tid & 63, w = tid >> 6;
  int m0 = blockIdx.y*128, n0 = blockIdx.x*128;
  int wm = (w >> 1)*64, wn = (w & 1)*64;
  int lr = lane & 15, lk = (lane >> 4)*8;
  int tr = tid >> 2, tc = (tid & 3)*8;
  f32x4 acc[4][4] = {};
  for (int k0 = 0; k0 < K; k0 += 32){
    __syncthreads();
    #pragma unroll
    for (int i = 0; i < 2; ++i){
      int r = tr + i*64;
      *reinterpret_cast<bf16x8*>(&As[r][tc]) =
        *reinterpret_cast<const bf16x8*>(&A[(size_t)(m0+r)*K + k0 + tc]);
      *reinterpret_cast<bf16x8*>(&Bs[r][tc]) =
        *reinterpret_cast<const bf16x8*>(&Bt[(size_t)(n0+r)*K + k0 + tc]);
    }
    __syncthreads();
    bf16x8 af[4], bfr[4];
    #pragma unroll
    for (int m = 0; m < 4; ++m)
      af[m] = *reinterpret_cast<bf16x8*>(&As[wm + m*16 + lr][lk]);
    #pragma unroll
    for (int n = 0; n < 4; ++n)
      bfr[n] = *reinterpret_cast<bf16x8*>(&Bs[wn + n*16 + lr][lk]);
    #pragma unroll
    for (int m = 0; m < 4; ++m)
      #pragma unroll
      for (int n = 0; n < 4; ++n)
        acc[m][n] = __builtin_amdgcn_mfma_f32_16x16x32_bf16(af[m], bfr[n], acc[m][n], 0, 0, 0);
  }
  #pragma unroll
  for (int m = 0; m < 4; ++m){
    #pragma unroll
    for (int n = 0; n < 4; ++n){
      #pragma unroll
      for (int r = 0; r < 4; ++r){
        int row = m0 + wm + m*16 + (lane >> 4)*4 + r;
        int col = n0 + wn + n*16 + lr;
        float v = acc[m][n][r] + bias[col];
        if (BF16_OUT) ob[(size_t)row*N + col] = f2bf(v);
        else          of[(size_t)row*N + col] = v;
      }
    }
  }
}

// ---- causal flash attention over qkv[B,S,3E] (per-head q|k|v 64 each) ----
__global__ __launch_bounds__(256) void attn_kernel(const ushort* __restrict__ qkv,
                                                   ushort* __restrict__ aout){
  __shared__ ushort Kl[64][72];
  __shared__ ushort Vt[64][72];
  __shared__ ushort Pl[64][72];
  int tid = threadIdx.x, lane = tid & 63, w = tid >> 6;
  int qb = blockIdx.x, bh = blockIdx.y;
  int b = bh >> 4, h = bh & 15;
  int q0 = qb*64;
  int lr = lane & 15, lg = lane >> 4;
  const size_t RS = (size_t)N1;

  bf16x8 qf[2];
  {
    int qrow = q0 + w*16 + lr;
    const ushort* qp = qkv + ((size_t)b*SS + qrow)*RS + h*192;
    qf[0] = *reinterpret_cast<const bf16x8*>(qp + lg*8);
    qf[1] = *reinterpret_cast<const bf16x8*>(qp + 32 + lg*8);
  }
  float mr[4], sr[4];
  f32x4 o[4] = {};
  #pragma unroll
  for (int r = 0; r < 4; ++r){ mr[r] = -1e30f; sr[r] = 0.f; }

  int str = tid >> 3, stc = (tid & 7)*8;
  for (int kb = 0; kb <= qb; ++kb){
    int k0 = kb*64;
    __syncthreads();
    #pragma unroll
    for (int i = 0; i < 2; ++i){
      int kk = str + i*32;
      const ushort* kp = qkv + ((size_t)b*SS + k0 + kk)*RS + h*192 + 64 + stc;
      *reinterpret_cast<bf16x8*>(&Kl[kk][stc]) = *reinterpret_cast<const bf16x8*>(kp);
      const ushort* vp = qkv + ((size_t)b*SS + k0 + kk)*RS + h*192 + 128 + stc;
      bf16x8 vv = *reinterpret_cast<const bf16x8*>(vp);
      #pragma unroll
      for (int j = 0; j < 8; ++j) Vt[stc + j][kk] = (ushort)vv[j];
    }
    __syncthreads();

    f32x4 sc[4] = {};
    #pragma unroll
    for (int ks = 0; ks < 2; ++ks){
      #pragma unroll
      for (int n = 0; n < 4; ++n){
        bf16x8 kf = *reinterpret_cast<bf16x8*>(&Kl[n*16 + lr][ks*32 + lg*8]);
        sc[n] = __builtin_amdgcn_mfma_f32_16x16x32_bf16(qf[ks], kf, sc[n], 0, 0, 0);
      }
    }
    // scale + causal mask (C layout: col=lane&15, row=(lane>>4)*4+reg)
    #pragma unroll
    for (int n = 0; n < 4; ++n){
      #pragma unroll
      for (int r = 0; r < 4; ++r){
        float v = sc[n][r]*0.125f;
        int colg = k0 + n*16 + lr;
        int rowg = q0 + w*16 + lg*4 + r;
        sc[n][r] = (colg > rowg) ? -1e30f : v;
      }
    }
    float tm[4];
    #pragma unroll
    for (int r = 0; r < 4; ++r)
      tm[r] = fmaxf(fmaxf(sc[0][r], sc[1][r]), fmaxf(sc[2][r], sc[3][r]));
    #pragma unroll
    for (int off = 1; off < 16; off <<= 1){
      #pragma unroll
      for (int r = 0; r < 4; ++r)
        tm[r] = fmaxf(tm[r], __shfl_xor(tm[r], off, 64));
    }
    float fac[4];
    #pragma unroll
    for (int r = 0; r < 4; ++r){
      float nm = fmaxf(mr[r], tm[r]);
      fac[r] = __expf(mr[r] - nm);
      mr[r] = nm;
    }
    float ts[4] = {0.f,0.f,0.f,0.f};
    #pragma unroll
    for (int n = 0; n < 4; ++n){
      #pragma unroll
      for (int r = 0; r < 4; ++r){
        float p = __expf(sc[n][r] - mr[r]);
        sc[n][r] = p;
        ts[r] += p;
      }
    }
    #pragma unroll
    for (int off = 1; off < 16; off <<= 1){
      #pragma unroll
      for (int r = 0; r < 4; ++r)
        ts[r] += __shfl_xor(ts[r], off, 64);
    }
    #pragma unroll
    for (int r = 0; r < 4; ++r) sr[r] = sr[r]*fac[r] + ts[r];

    // P -> LDS (re-fragment for PV)
    #pragma unroll
    for (int n = 0; n < 4; ++n){
      #pragma unroll
      for (int r = 0; r < 4; ++r)
        Pl[w*16 + lg*4 + r][n*16 + lr] = f2bf(sc[n][r]);
    }
    __syncthreads();
    #pragma unroll
    for (int n = 0; n < 4; ++n){
      #pragma unroll
      for (int r = 0; r < 4; ++r)
        o[n][r] *= fac[r];
    }
    #pragma unroll
    for (int ks = 0; ks < 2; ++ks){
      bf16x8 pf = *reinterpret_cast<bf16x8*>(&Pl[w*16 + lr][ks*32 + lg*8]);
      #pragma unroll
      for (int n = 0; n < 4; ++n){
        bf16x8 vf = *reinterpret_cast<bf16x8*>(&Vt[n*16 + lr][ks*32 + lg*8]);
        o[n] = __builtin_amdgcn_mfma_f32_16x16x32_bf16(pf, vf, o[n], 0, 0, 0);
      }
    }
  }
  #pragma unroll
  for (int n = 0; n < 4; ++n){
    #pragma unroll
    for (int r = 0; r < 4; ++r){
      int rowg = q0 + w*16 + lg*4 + r;
      aout[((size_t)b*SS + rowg)*EE + h*DD + n*16 + lr] = f2bf(o[n][r]/sr[r]);
    }
  }
}

extern "C" void kernel_launch(void* const* d_in, const int* in_sizes, int n_in,
                              void* d_out, int out_size, void* d_ws, size_t ws_size,
                              hipStream_t stream){
  const float* x      = (const float*)d_in[0];
  const float* w_attn = (const float*)d_in[1];
  const float* b_attn = (const float*)d_in[2];
  const float* w_proj = (const float*)d_in[3];
  const float* b_proj = (const float*)d_in[4];
  float* out = (float*)d_out;

  ushort* ws   = (ushort*)d_ws;
  ushort* xb   = ws;                          // [4096,1024] bf16
  ushort* waT  = xb  + (size_t)MM*EE;         // [3072,1024] bf16 (w_attn^T)
  ushort* wpT  = waT + (size_t)N1*EE;         // [1024,1024] bf16 (w_proj^T)
  ushort* qkvb = wpT + (size_t)EE*EE;         // [4096,3072] bf16
  ushort* ab   = qkvb + (size_t)MM*N1;        // [4096,1024] bf16

  cvt_kernel<<<(MM*EE/4 + 255)/256, 256, 0, stream>>>(x, xb, MM*EE/4);
  dim3 bt(32, 8);
  cvtT_kernel<<<dim3(N1/32, EE/32), bt, 0, stream>>>(w_attn, waT, EE, N1);
  cvtT_kernel<<<dim3(EE/32, EE/32), bt, 0, stream>>>(w_proj, wpT, EE, EE);

  gemm_nt<1><<<dim3(N1/128, MM/128), 256, 0, stream>>>(xb, waT, b_attn, qkvb, nullptr, MM, N1, EE);
  attn_kernel<<<dim3(SS/64, BB*HH), 256, 0, stream>>>(qkvb, ab);
  gemm_nt<0><<<dim3(EE/128, MM/128), 256, 0, stream>>>(ab, wpT, b_proj, nullptr, out, MM, EE, EE);
}

// Round 3
// 164.795 us; speedup vs baseline: 1.5482x; 1.5482x over previous
//
#include <hip/hip_runtime.h>
#include <hip/hip_bf16.h>

#define BB 2
#define SS 2048
#define EE 1024
#define HH 16
#define DD 64
#define MM (BB*SS)      // 4096
#define N1 (3*EE)       // 3072

typedef __attribute__((ext_vector_type(4))) float f32x4;
typedef __attribute__((ext_vector_type(16))) float f32x16;
typedef __attribute__((ext_vector_type(8))) short bf16x8;
typedef __attribute__((ext_vector_type(4))) unsigned int u32x4;

__device__ __forceinline__ ushort f2bf(float f){
  union { float f; unsigned u; } v; v.f = f;
  unsigned r = v.u + 0x7fffu + ((v.u >> 16) & 1u);
  return (ushort)(r >> 16);
}

__device__ __forceinline__ unsigned cvt_pk(float a, float b){
  unsigned r; asm("v_cvt_pk_bf16_f32 %0, %1, %2" : "=v"(r) : "v"(a), "v"(b)); return r;
}

// ---- fp32 -> bf16 straight convert (vectorized x4) ----
__global__ void cvt_kernel(const float* __restrict__ in, ushort* __restrict__ out, int n4){
  int i = blockIdx.x*blockDim.x + threadIdx.x;
  if (i < n4){
    const float4 f = reinterpret_cast<const float4*>(in)[i];
    ushort4 o;
    o.x = f2bf(f.x); o.y = f2bf(f.y); o.z = f2bf(f.z); o.w = f2bf(f.w);
    reinterpret_cast<ushort4*>(out)[i] = o;
  }
}

// ---- fp32 [K,N] -> bf16 [N,K] transposed convert, 32x32 LDS tiles ----
__global__ void cvtT_kernel(const float* __restrict__ in, ushort* __restrict__ out, int K, int N){
  __shared__ float t[32][33];
  int n0 = blockIdx.x*32, k0 = blockIdx.y*32;
  int tx = threadIdx.x, ty = threadIdx.y;
  for (int r = ty; r < 32; r += 8)
    t[r][tx] = in[(size_t)(k0+r)*N + n0 + tx];
  __syncthreads();
  for (int r = ty; r < 32; r += 8)
    out[(size_t)(n0+r)*K + k0 + tx] = f2bf(t[tx][r]);
}

// ---- bf16 GEMM: C[M,N] = A[M,K]*Bt[N,K]^T + bias.
// MODE 0: scatter to Q[B,H,S,64], K[B,H,S,64], V^T[B,H,64,S] (bf16)
// MODE 1: fp32 row-major out
template<int MODE>
__global__ __launch_bounds__(256) void gemm_nt(const ushort* __restrict__ A,
    const ushort* __restrict__ Bt, const float* __restrict__ bias,
    ushort* __restrict__ q_, ushort* __restrict__ k_, ushort* __restrict__ v_,
    float* __restrict__ of, int M, int N, int K){
  __shared__ ushort As[128][40];
  __shared__ ushort Bs[128][40];
  int tid = threadIdx.x;
  int lane = tid & 63, w = tid >> 6;
  int m0 = blockIdx.y*128, n0 = blockIdx.x*128;
  int wm = (w >> 1)*64, wn = (w & 1)*64;
  int lr = lane & 15, lk = (lane >> 4)*8;
  int tr = tid >> 2, tc = (tid & 3)*8;
  f32x4 acc[4][4] = {};
  for (int k0 = 0; k0 < K; k0 += 32){
    __syncthreads();
    #pragma unroll
    for (int i = 0; i < 2; ++i){
      int r = tr + i*64;
      *reinterpret_cast<bf16x8*>(&As[r][tc]) =
        *reinterpret_cast<const bf16x8*>(&A[(size_t)(m0+r)*K + k0 + tc]);
      *reinterpret_cast<bf16x8*>(&Bs[r][tc]) =
        *reinterpret_cast<const bf16x8*>(&Bt[(size_t)(n0+r)*K + k0 + tc]);
    }
    __syncthreads();
    bf16x8 af[4], bfr[4];
    #pragma unroll
    for (int m = 0; m < 4; ++m)
      af[m] = *reinterpret_cast<bf16x8*>(&As[wm + m*16 + lr][lk]);
    #pragma unroll
    for (int n = 0; n < 4; ++n)
      bfr[n] = *reinterpret_cast<bf16x8*>(&Bs[wn + n*16 + lr][lk]);
    #pragma unroll
    for (int m = 0; m < 4; ++m)
      #pragma unroll
      for (int n = 0; n < 4; ++n)
        acc[m][n] = __builtin_amdgcn_mfma_f32_16x16x32_bf16(af[m], bfr[n], acc[m][n], 0, 0, 0);
  }
  #pragma unroll
  for (int m = 0; m < 4; ++m){
    #pragma unroll
    for (int n = 0; n < 4; ++n){
      int col = n0 + wn + n*16 + lr;
      float bv = bias[col];
      #pragma unroll
      for (int r = 0; r < 4; ++r){
        int row = m0 + wm + m*16 + (lane >> 4)*4 + r;
        float v = acc[m][n][r] + bv;
        if (MODE == 1){
          of[(size_t)row*N + col] = v;
        } else {
          int b = row >> 11, s = row & 2047;
          int h = col / 192, t = col - h*192;
          ushort u = f2bf(v);
          size_t bh = (size_t)(b*HH + h);
          if (t < 64)       q_[(bh*SS + s)*DD + t]        = u;
          else if (t < 128) k_[(bh*SS + s)*DD + (t-64)]   = u;
          else              v_[(bh*DD + (t-128))*SS + s]  = u;
        }
      }
    }
  }
}

// ---- causal flash attention, swapped-QK 32x32 structure ----
// grid: (x=32 bh, y=16 qt-slot). 4 waves x 32 q-rows = 128 q/block. KVBLK=64.
__global__ __launch_bounds__(256,2) void attn2(const ushort* __restrict__ Qg,
    const ushort* __restrict__ Kg, const ushort* __restrict__ Vg,
    ushort* __restrict__ aout){
  __shared__ __align__(16) ushort Kl[64*64];
  __shared__ __align__(16) ushort Vl[64*64];
  const int tid = threadIdx.x, lane = tid & 63, w = tid >> 6;
  const int bh = blockIdx.x;
  const int y  = blockIdx.y;
  const int qt = (y < 8) ? 2*y : 31 - 2*y;          // complementary pairing
  const int b = bh >> 4, h = bh & 15;
  const int q0 = qt*128;
  const int ql = lane & 31, g = lane >> 5;
  const int qrow = q0 + w*32 + ql;
  const int qminw = q0 + w*32;
  const int qmaxw = qminw + 31;

  // Q B-fragments: lane holds Q[qrow][16s + 8g + j], j=0..7
  const ushort* Qp = Qg + ((size_t)bh*SS + qrow)*DD;
  bf16x8 qf[4];
  #pragma unroll
  for (int s = 0; s < 4; ++s)
    qf[s] = *(const bf16x8*)(Qp + s*16 + g*8);

  f32x16 ot[2] = {};
  float mr = -1e30f, sr = 0.f;

  const int srow = tid >> 3, scb = tid & 7;
  const ushort* Kbase = Kg + (size_t)bh*SS*DD;
  const ushort* Vbase = Vg + (size_t)bh*DD*SS;
  const int nkb = (q0 + 128) >> 6;

  for (int kb = 0; kb < nkb; ++kb){
    const int k0 = kb*64;
    __syncthreads();
    #pragma unroll
    for (int i = 0; i < 2; ++i){
      int r = srow + i*32;
      int sw = (scb ^ (r & 7))*8;
      *(bf16x8*)&Kl[r*64 + sw] = *(const bf16x8*)(Kbase + (size_t)(k0 + r)*DD + scb*8);
      *(bf16x8*)&Vl[r*64 + sw] = *(const bf16x8*)(Vbase + (size_t)r*SS + k0 + scb*8);
    }
    __syncthreads();
    if (k0 > qmaxw) continue;   // fully masked for this wave (barrier count stays uniform)

    // S^T = K * Q^T : 2 k-frags x 4 d-steps
    f32x16 st0 = {}, st1 = {};
    const int swq = (ql & 7);
    #pragma unroll
    for (int s = 0; s < 4; ++s){
      bf16x8 kf0 = *(const bf16x8*)&Kl[ ql     *64 + (((2*s + g) ^ swq)*8)];
      bf16x8 kf1 = *(const bf16x8*)&Kl[(32+ql) *64 + (((2*s + g) ^ swq)*8)];
      st0 = __builtin_amdgcn_mfma_f32_32x32x16_bf16(kf0, qf[s], st0, 0, 0, 0);
      st1 = __builtin_amdgcn_mfma_f32_32x32x16_bf16(kf1, qf[s], st1, 0, 0, 0);
    }
    float p[2][16];
    #pragma unroll
    for (int r = 0; r < 16; ++r){ p[0][r] = st0[r]*0.125f; p[1][r] = st1[r]*0.125f; }
    if (k0 + 63 > qminw){   // FIXED: tile is diagonal unless k0+63 <= wave's MIN row
      #pragma unroll
      for (int kf = 0; kf < 2; ++kf)
        #pragma unroll
        for (int r = 0; r < 16; ++r){
          int kg = k0 + kf*32 + (r & 3) + 8*(r >> 2) + 4*g;
          p[kf][r] = (kg > qrow) ? -1e30f : p[kf][r];
        }
    }
    // row max (tree) + half-swap
    float m8[8];
    #pragma unroll
    for (int i = 0; i < 8; ++i)
      m8[i] = fmaxf(fmaxf(p[0][i], p[0][i+8]), fmaxf(p[1][i], p[1][i+8]));
    float tm = fmaxf(fmaxf(fmaxf(m8[0],m8[1]), fmaxf(m8[2],m8[3])),
                     fmaxf(fmaxf(m8[4],m8[5]), fmaxf(m8[6],m8[7])));
    tm = fmaxf(tm, __shfl_xor(tm, 32));
    float nm = fmaxf(mr, tm);
    float fac = __expf(mr - nm);
    mr = nm;
    #pragma unroll
    for (int kf = 0; kf < 2; ++kf)
      #pragma unroll
      for (int r = 0; r < 16; ++r)
        p[kf][r] = __expf(p[kf][r] - nm);
    float s8[8];
    #pragma unroll
    for (int i = 0; i < 8; ++i)
      s8[i] = (p[0][i] + p[0][i+8]) + (p[1][i] + p[1][i+8]);
    float ts = ((s8[0]+s8[1]) + (s8[2]+s8[3])) + ((s8[4]+s8[5]) + (s8[6]+s8[7]));
    ts += __shfl_xor(ts, 32);
    sr = sr*fac + ts;
    #pragma unroll
    for (int r = 0; r < 16; ++r){ ot[0][r] *= fac; ot[1][r] *= fac; }

    // PV: O^T += V^T * P^T, P rebuilt in-register
    #pragma unroll
    for (int kf = 0; kf < 2; ++kf){
      #pragma unroll
      for (int s2 = 0; s2 < 2; ++s2){
        const int base = s2*8;
        unsigned a0 = cvt_pk(p[kf][base+0], p[kf][base+1]);
        unsigned b0 = cvt_pk(p[kf][base+2], p[kf][base+3]);
        unsigned a1 = cvt_pk(p[kf][base+4], p[kf][base+5]);
        unsigned b1 = cvt_pk(p[kf][base+6], p[kf][base+7]);
        unsigned a0o = __shfl_xor(a0, 32), b0o = __shfl_xor(b0, 32);
        unsigned a1o = __shfl_xor(a1, 32), b1o = __shfl_xor(b1, 32);
        union { u32x4 u; bf16x8 hv; } pw;
        pw.u[0] = g ? a1o : a0;
        pw.u[1] = g ? b1o : b0;
        pw.u[2] = g ? a1  : a0o;
        pw.u[3] = g ? b1  : b0o;
        const int cbv = 4*kf + 2*s2 + g;
        bf16x8 v0f = *(const bf16x8*)&Vl[ ql     *64 + ((cbv ^ swq)*8)];
        bf16x8 v1f = *(const bf16x8*)&Vl[(32+ql) *64 + ((cbv ^ swq)*8)];
        ot[0] = __builtin_amdgcn_mfma_f32_32x32x16_bf16(v0f, pw.hv, ot[0], 0, 0, 0);
        ot[1] = __builtin_amdgcn_mfma_f32_32x32x16_bf16(v1f, pw.hv, ot[1], 0, 0, 0);
      }
    }
  }
  const float inv = 1.f / sr;
  const size_t obase = ((size_t)b*SS + qrow)*EE + h*DD;
  #pragma unroll
  for (int df = 0; df < 2; ++df){
    #pragma unroll
    for (int t = 0; t < 4; ++t){
      ushort4 o4;
      o4.x = f2bf(ot[df][t*4+0]*inv);
      o4.y = f2bf(ot[df][t*4+1]*inv);
      o4.z = f2bf(ot[df][t*4+2]*inv);
      o4.w = f2bf(ot[df][t*4+3]*inv);
      int d = df*32 + 8*t + 4*g;
      *(ushort4*)&aout[obase + d] = o4;
    }
  }
}

extern "C" void kernel_launch(void* const* d_in, const int* in_sizes, int n_in,
                              void* d_out, int out_size, void* d_ws, size_t ws_size,
                              hipStream_t stream){
  const float* x      = (const float*)d_in[0];
  const float* w_attn = (const float*)d_in[1];
  const float* b_attn = (const float*)d_in[2];
  const float* w_proj = (const float*)d_in[3];
  const float* b_proj = (const float*)d_in[4];
  float* out = (float*)d_out;

  ushort* ws   = (ushort*)d_ws;
  ushort* xb   = ws;                           // [4096,1024] bf16
  ushort* waT  = xb  + (size_t)MM*EE;          // [3072,1024] bf16 (w_attn^T)
  ushort* wpT  = waT + (size_t)N1*EE;          // [1024,1024] bf16 (w_proj^T)
  ushort* qb_  = wpT + (size_t)EE*EE;          // Q  [B,H,S,64]
  ushort* kb_  = qb_ + (size_t)MM*EE;          // K  [B,H,S,64]
  ushort* vTb  = kb_ + (size_t)MM*EE;          // V^T[B,H,64,S]
  ushort* ab   = vTb + (size_t)MM*EE;          // attn out [B,S,E]

  cvt_kernel<<<(MM*EE/4 + 255)/256, 256, 0, stream>>>(x, xb, MM*EE/4);
  dim3 bt(32, 8);
  cvtT_kernel<<<dim3(N1/32, EE/32), bt, 0, stream>>>(w_attn, waT, EE, N1);
  cvtT_kernel<<<dim3(EE/32, EE/32), bt, 0, stream>>>(w_proj, wpT, EE, EE);

  gemm_nt<0><<<dim3(N1/128, MM/128), 256, 0, stream>>>(xb, waT, b_attn, qb_, kb_, vTb, nullptr, MM, N1, EE);
  attn2<<<dim3(BB*HH, SS/128), 256, 0, stream>>>(qb_, kb_, vTb, ab);
  gemm_nt<1><<<dim3(EE/128, MM/128), 256, 0, stream>>>(ab, wpT, b_proj, nullptr, nullptr, nullptr, out, MM, EE, EE);
}

// Round 4
// 138.512 us; speedup vs baseline: 1.8420x; 1.1898x over previous
//
#include <hip/hip_runtime.h>
#include <hip/hip_bf16.h>

#define BB 2
#define SS 2048
#define EE 1024
#define HH 16
#define DD 64
#define MM (BB*SS)      // 4096
#define N1 (3*EE)       // 3072

typedef __attribute__((ext_vector_type(4))) float f32x4;
typedef __attribute__((ext_vector_type(16))) float f32x16;
typedef __attribute__((ext_vector_type(8))) short bf16x8;
typedef __attribute__((ext_vector_type(4))) unsigned int u32x4;

__device__ __forceinline__ ushort f2bf(float f){
  union { float f; unsigned u; } v; v.f = f;
  unsigned r = v.u + 0x7fffu + ((v.u >> 16) & 1u);
  return (ushort)(r >> 16);
}

__device__ __forceinline__ unsigned cvt_pk(float a, float b){
  unsigned r; asm("v_cvt_pk_bf16_f32 %0, %1, %2" : "=v"(r) : "v"(a), "v"(b)); return r;
}

__device__ __forceinline__ float exp2_fast(float x){
  float r; asm("v_exp_f32 %0, %1" : "=v"(r) : "v"(x)); return r;
}

// async global->LDS, 16B per lane. LDS dest = wave-uniform base + lane*16.
__device__ __forceinline__ void gload16(const void* g, void* l){
  __builtin_amdgcn_global_load_lds(
      (const __attribute__((address_space(1))) unsigned*)g,
      (__attribute__((address_space(3))) unsigned*)l, 16, 0, 0);
}

// ---- fp32 -> bf16 straight convert (vectorized x4) ----
__global__ void cvt_kernel(const float* __restrict__ in, ushort* __restrict__ out, int n4){
  int i = blockIdx.x*blockDim.x + threadIdx.x;
  if (i < n4){
    const float4 f = reinterpret_cast<const float4*>(in)[i];
    ushort4 o;
    o.x = f2bf(f.x); o.y = f2bf(f.y); o.z = f2bf(f.z); o.w = f2bf(f.w);
    reinterpret_cast<ushort4*>(out)[i] = o;
  }
}

// ---- fp32 [K,N] -> bf16 [N,K] transposed convert, 32x32 LDS tiles ----
__global__ void cvtT_kernel(const float* __restrict__ in, ushort* __restrict__ out, int K, int N){
  __shared__ float t[32][33];
  int n0 = blockIdx.x*32, k0 = blockIdx.y*32;
  int tx = threadIdx.x, ty = threadIdx.y;
  for (int r = ty; r < 32; r += 8)
    t[r][tx] = in[(size_t)(k0+r)*N + n0 + tx];
  __syncthreads();
  for (int r = ty; r < 32; r += 8)
    out[(size_t)(n0+r)*K + k0 + tx] = f2bf(t[tx][r]);
}

// ---- bf16 GEMM (m97 structure): C = A[M,K]*Bt[N,K]^T + bias.
// global_load_lds width-16 staging into linear LDS [128][32], 2 barriers/K-step.
// MODE 0: scatter to Q[B,H,S,64], K[B,H,S,64], V^T[B,H,64,S] (bf16)
// MODE 1: fp32 row-major out
template<int MODE>
__global__ __launch_bounds__(256) void gemm_nt(const ushort* __restrict__ A,
    const ushort* __restrict__ Bt, const float* __restrict__ bias,
    ushort* __restrict__ q_, ushort* __restrict__ k_, ushort* __restrict__ v_,
    float* __restrict__ of, int M, int N, int K){
  __shared__ ushort As[128*32];
  __shared__ ushort Bs[128*32];
  const int tid = threadIdx.x;
  const int lane = tid & 63, w = tid >> 6;
  // bijective XCD swizzle (nwg % 8 == 0 for both launches: 768, 256)
  const int nx = gridDim.x;
  const int nwg = nx * gridDim.y;
  const int flat = blockIdx.y*nx + blockIdx.x;
  const int sw = (flat & 7)*(nwg >> 3) + (flat >> 3);
  const int m0 = (sw / nx)*128, n0 = (sw % nx)*128;
  const int wm = (w >> 1)*64, wn = (w & 1)*64;
  const int lr = lane & 15, lk = (lane >> 4)*8;
  // staging: 8 chunks of 1KB per operand; wave w owns chunks {2w, 2w+1}
  const int c0 = w*2;
  const int srow = lane >> 2;          // 0..15 (4 lanes per 64B row)
  const int scb  = (lane & 3)*8;       // ushort col offset (16B units)
  const ushort* Ag0 = A  + (size_t)(m0 + c0*16      + srow)*K + scb;
  const ushort* Ag1 = A  + (size_t)(m0 + c0*16 + 16 + srow)*K + scb;
  const ushort* Bg0 = Bt + (size_t)(n0 + c0*16      + srow)*K + scb;
  const ushort* Bg1 = Bt + (size_t)(n0 + c0*16 + 16 + srow)*K + scb;
  ushort* Al0 = &As[(c0*16)*32];
  ushort* Al1 = &As[(c0*16 + 16)*32];
  ushort* Bl0 = &Bs[(c0*16)*32];
  ushort* Bl1 = &Bs[(c0*16 + 16)*32];

  f32x4 acc[4][4] = {};
  for (int k0 = 0; k0 < K; k0 += 32){
    gload16(Ag0 + k0, Al0);
    gload16(Ag1 + k0, Al1);
    gload16(Bg0 + k0, Bl0);
    gload16(Bg1 + k0, Bl1);
    __syncthreads();                 // vmcnt(0) drain + all waves staged
    bf16x8 af[4], bfr[4];
    #pragma unroll
    for (int m = 0; m < 4; ++m)
      af[m] = *reinterpret_cast<bf16x8*>(&As[(wm + m*16 + lr)*32 + lk]);
    #pragma unroll
    for (int n = 0; n < 4; ++n)
      bfr[n] = *reinterpret_cast<bf16x8*>(&Bs[(wn + n*16 + lr)*32 + lk]);
    #pragma unroll
    for (int m = 0; m < 4; ++m)
      #pragma unroll
      for (int n = 0; n < 4; ++n)
        acc[m][n] = __builtin_amdgcn_mfma_f32_16x16x32_bf16(af[m], bfr[n], acc[m][n], 0, 0, 0);
    __syncthreads();                 // reads done before next stage overwrites
  }
  #pragma unroll
  for (int m = 0; m < 4; ++m){
    #pragma unroll
    for (int n = 0; n < 4; ++n){
      int col = n0 + wn + n*16 + lr;
      float bv = bias[col];
      #pragma unroll
      for (int r = 0; r < 4; ++r){
        int row = m0 + wm + m*16 + (lane >> 4)*4 + r;
        float v = acc[m][n][r] + bv;
        if (MODE == 1){
          of[(size_t)row*N + col] = v;
        } else {
          int b = row >> 11, s = row & 2047;
          int h = col / 192, t = col - h*192;
          ushort u = f2bf(v);
          size_t bh = (size_t)(b*HH + h);
          if (t < 64)       q_[(bh*SS + s)*DD + t]        = u;
          else if (t < 128) k_[(bh*SS + s)*DD + (t-64)]   = u;
          else              v_[(bh*DD + (t-128))*SS + s]  = u;
        }
      }
    }
  }
}

// ---- causal flash attention, swapped-QK 32x32, dbuf + async staging ----
// grid: (x=32 bh, y=16 qt-slot). 4 waves x 32 q-rows = 128 q/block. KVBLK=64.
#define SCL 0.18033688f          /* log2(e)/8 */
#define THRRAW 44.3614f          /* 8 / SCL   */
__global__ __launch_bounds__(256,2) void attn2(const ushort* __restrict__ Qg,
    const ushort* __restrict__ Kg, const ushort* __restrict__ Vg,
    ushort* __restrict__ aout){
  __shared__ __align__(16) ushort Kl[2][64*64];
  __shared__ __align__(16) ushort Vl[2][64*64];
  const int tid = threadIdx.x, lane = tid & 63, w = tid >> 6;
  const int bh = blockIdx.x;
  const int y  = blockIdx.y;
  const int qt = (y < 8) ? 2*y : 31 - 2*y;          // complementary pairing
  const int b = bh >> 4, h = bh & 15;
  const int q0 = qt*128;
  const int ql = lane & 31, g = lane >> 5;
  const int qrow = q0 + w*32 + ql;
  const int qminw = q0 + w*32;
  const int qmaxw = qminw + 31;

  const ushort* Qp = Qg + ((size_t)bh*SS + qrow)*DD;
  bf16x8 qf[4];
  #pragma unroll
  for (int s = 0; s < 4; ++s)
    qf[s] = *(const bf16x8*)(Qp + s*16 + g*8);

  f32x16 ot[2] = {};
  float mr = -1e30f, sr = 0.f;

  // staging coords: 8 chunks of 1KB per tile per operand; wave owns {2w,2w+1}
  const int csr = lane >> 3;               // row within chunk (0..7)
  const int gcb = ((lane & 7) ^ csr)*8;    // pre-swizzled global col (ushorts)
  const ushort* Kbase = Kg + (size_t)bh*SS*DD;
  const ushort* Vbase = Vg + (size_t)bh*DD*SS;
  const int nkb = (q0 + 128) >> 6;

  auto stage = [&](int k0, int bi){
    #pragma unroll
    for (int i = 0; i < 2; ++i){
      const int c = w*2 + i;
      gload16(Kbase + (size_t)(k0 + c*8 + csr)*DD + gcb, &Kl[bi][(c*8)*64]);
      gload16(Vbase + (size_t)(c*8 + csr)*SS + k0 + gcb, &Vl[bi][(c*8)*64]);
    }
  };

  stage(0, 0);
  int buf = 0;
  for (int kb = 0; kb < nkb; ++kb){
    const int k0 = kb*64;
    __syncthreads();                      // stage(kb) landed; prev reads done
    if (kb + 1 < nkb) stage(k0 + 64, buf ^ 1);
    if (k0 <= qmaxw){
      const ushort* Kc = &Kl[buf][0];
      const ushort* Vc = &Vl[buf][0];
      const int swq = (ql & 7);
      // S^T = K * Q^T
      f32x16 st0 = {}, st1 = {};
      #pragma unroll
      for (int s = 0; s < 4; ++s){
        bf16x8 kf0 = *(const bf16x8*)&Kc[ ql     *64 + (((2*s + g) ^ swq)*8)];
        bf16x8 kf1 = *(const bf16x8*)&Kc[(32+ql) *64 + (((2*s + g) ^ swq)*8)];
        st0 = __builtin_amdgcn_mfma_f32_32x32x16_bf16(kf0, qf[s], st0, 0, 0, 0);
        st1 = __builtin_amdgcn_mfma_f32_32x32x16_bf16(kf1, qf[s], st1, 0, 0, 0);
      }
      float p[2][16];
      #pragma unroll
      for (int r = 0; r < 16; ++r){ p[0][r] = st0[r]; p[1][r] = st1[r]; }  // raw scores
      if (k0 + 63 > qminw){
        #pragma unroll
        for (int kf = 0; kf < 2; ++kf)
          #pragma unroll
          for (int r = 0; r < 16; ++r){
            int kg = k0 + kf*32 + (r & 3) + 8*(r >> 2) + 4*g;
            p[kf][r] = (kg > qrow) ? -1e30f : p[kf][r];
          }
      }
      // tile row-max (raw units)
      float m8[8];
      #pragma unroll
      for (int i = 0; i < 8; ++i)
        m8[i] = fmaxf(fmaxf(p[0][i], p[0][i+8]), fmaxf(p[1][i], p[1][i+8]));
      float tm = fmaxf(fmaxf(fmaxf(m8[0],m8[1]), fmaxf(m8[2],m8[3])),
                       fmaxf(fmaxf(m8[4],m8[5]), fmaxf(m8[6],m8[7])));
      tm = fmaxf(tm, __shfl_xor(tm, 32));
      // defer-max: rescale only if growth exceeds 2^8 headroom
      if (__any(tm > mr + THRRAW)){
        float nm = fmaxf(mr, tm);
        float fac = exp2_fast((mr - nm)*SCL);
        #pragma unroll
        for (int r = 0; r < 16; ++r){ ot[0][r] *= fac; ot[1][r] *= fac; }
        sr *= fac;
        mr = nm;
      }
      const float nms = mr * SCL;
      #pragma unroll
      for (int kf = 0; kf < 2; ++kf)
        #pragma unroll
        for (int r = 0; r < 16; ++r)
          p[kf][r] = exp2_fast(__builtin_fmaf(p[kf][r], SCL, -nms));
      float s8[8];
      #pragma unroll
      for (int i = 0; i < 8; ++i)
        s8[i] = (p[0][i] + p[0][i+8]) + (p[1][i] + p[1][i+8]);
      float ts = ((s8[0]+s8[1]) + (s8[2]+s8[3])) + ((s8[4]+s8[5]) + (s8[6]+s8[7]));
      ts += __shfl_xor(ts, 32);
      sr += ts;

      // PV: O^T += V^T * P^T, P rebuilt in-register
      #pragma unroll
      for (int kf = 0; kf < 2; ++kf){
        #pragma unroll
        for (int s2 = 0; s2 < 2; ++s2){
          const int base = s2*8;
          unsigned a0 = cvt_pk(p[kf][base+0], p[kf][base+1]);
          unsigned b0 = cvt_pk(p[kf][base+2], p[kf][base+3]);
          unsigned a1 = cvt_pk(p[kf][base+4], p[kf][base+5]);
          unsigned b1 = cvt_pk(p[kf][base+6], p[kf][base+7]);
          unsigned a0o = __shfl_xor(a0, 32), b0o = __shfl_xor(b0, 32);
          unsigned a1o = __shfl_xor(a1, 32), b1o = __shfl_xor(b1, 32);
          union { u32x4 u; bf16x8 hv; } pw;
          pw.u[0] = g ? a1o : a0;
          pw.u[1] = g ? b1o : b0;
          pw.u[2] = g ? a1  : a0o;
          pw.u[3] = g ? b1  : b0o;
          const int cbv = 4*kf + 2*s2 + g;
          bf16x8 v0f = *(const bf16x8*)&Vc[ ql     *64 + ((cbv ^ swq)*8)];
          bf16x8 v1f = *(const bf16x8*)&Vc[(32+ql) *64 + ((cbv ^ swq)*8)];
          ot[0] = __builtin_amdgcn_mfma_f32_32x32x16_bf16(v0f, pw.hv, ot[0], 0, 0, 0);
          ot[1] = __builtin_amdgcn_mfma_f32_32x32x16_bf16(v1f, pw.hv, ot[1], 0, 0, 0);
        }
      }
    }
    buf ^= 1;
  }
  const float inv = 1.f / sr;
  const size_t obase = ((size_t)b*SS + qrow)*EE + h*DD;
  #pragma unroll
  for (int df = 0; df < 2; ++df){
    #pragma unroll
    for (int t = 0; t < 4; ++t){
      ushort4 o4;
      o4.x = f2bf(ot[df][t*4+0]*inv);
      o4.y = f2bf(ot[df][t*4+1]*inv);
      o4.z = f2bf(ot[df][t*4+2]*inv);
      o4.w = f2bf(ot[df][t*4+3]*inv);
      int d = df*32 + 8*t + 4*g;
      *(ushort4*)&aout[obase + d] = o4;
    }
  }
}

extern "C" void kernel_launch(void* const* d_in, const int* in_sizes, int n_in,
                              void* d_out, int out_size, void* d_ws, size_t ws_size,
                              hipStream_t stream){
  const float* x      = (const float*)d_in[0];
  const float* w_attn = (const float*)d_in[1];
  const float* b_attn = (const float*)d_in[2];
  const float* w_proj = (const float*)d_in[3];
  const float* b_proj = (const float*)d_in[4];
  float* out = (float*)d_out;

  ushort* ws   = (ushort*)d_ws;
  ushort* xb   = ws;                           // [4096,1024] bf16
  ushort* waT  = xb  + (size_t)MM*EE;          // [3072,1024] bf16 (w_attn^T)
  ushort* wpT  = waT + (size_t)N1*EE;          // [1024,1024] bf16 (w_proj^T)
  ushort* qb_  = wpT + (size_t)EE*EE;          // Q  [B,H,S,64]
  ushort* kb_  = qb_ + (size_t)MM*EE;          // K  [B,H,S,64]
  ushort* vTb  = kb_ + (size_t)MM*EE;          // V^T[B,H,64,S]
  ushort* ab   = vTb + (size_t)MM*EE;          // attn out [B,S,E]

  cvt_kernel<<<(MM*EE/4 + 255)/256, 256, 0, stream>>>(x, xb, MM*EE/4);
  dim3 bt(32, 8);
  cvtT_kernel<<<dim3(N1/32, EE/32), bt, 0, stream>>>(w_attn, waT, EE, N1);
  cvtT_kernel<<<dim3(EE/32, EE/32), bt, 0, stream>>>(w_proj, wpT, EE, EE);

  gemm_nt<0><<<dim3(N1/128, MM/128), 256, 0, stream>>>(xb, waT, b_attn, qb_, kb_, vTb, nullptr, MM, N1, EE);
  attn2<<<dim3(BB*HH, SS/128), 256, 0, stream>>>(qb_, kb_, vTb, ab);
  gemm_nt<1><<<dim3(EE/128, MM/128), 256, 0, stream>>>(ab, wpT, b_proj, nullptr, nullptr, nullptr, out, MM, EE, EE);
}

// Round 7
// 123.080 us; speedup vs baseline: 2.0729x; 1.1254x over previous
//
#include <hip/hip_runtime.h>
#include <hip/hip_bf16.h>

#define BB 2
#define SS 2048
#define EE 1024
#define HH 16
#define DD 64
#define MM (BB*SS)      // 4096
#define N1 (3*EE)       // 3072

typedef __attribute__((ext_vector_type(4))) float f32x4;
typedef __attribute__((ext_vector_type(16))) float f32x16;
typedef __attribute__((ext_vector_type(8))) short bf16x8;
typedef __attribute__((ext_vector_type(4))) unsigned int u32x4;
typedef __attribute__((ext_vector_type(2))) unsigned int u32x2;

__device__ __forceinline__ ushort f2bf(float f){
  union { float f; unsigned u; } v; v.f = f;
  unsigned r = v.u + 0x7fffu + ((v.u >> 16) & 1u);
  return (ushort)(r >> 16);
}

__device__ __forceinline__ unsigned cvt_pk(float a, float b){
  unsigned r; asm("v_cvt_pk_bf16_f32 %0, %1, %2" : "=v"(r) : "v"(a), "v"(b)); return r;
}

__device__ __forceinline__ float exp2_fast(float x){
  float r; asm("v_exp_f32 %0, %1" : "=v"(r) : "v"(x)); return r;
}

// v_permlane32_swap_b32 true semantics (lane-half exchange, 32-bit values):
// {na, nb} = pl32swap(a, b):
//   na[l] = a[l]      (l<32) ;  na[l] = b[l-32] (l>=32)
//   nb[l] = a[l+32]   (l<32) ;  nb[l] = b[l]    (l>=32)
__device__ __forceinline__ u32x2 pl32swap(unsigned a, unsigned b){
  return __builtin_amdgcn_permlane32_swap(a, b, false, false);
}

// async global->LDS, 16B per lane. LDS dest = wave-uniform base + lane*16.
__device__ __forceinline__ void gload16(const void* g, void* l){
  __builtin_amdgcn_global_load_lds(
      (const __attribute__((address_space(1))) unsigned*)g,
      (__attribute__((address_space(3))) unsigned*)l, 16, 0, 0);
}

// ---- fused prep: x->bf16 (blocks 0..4095), w_attn^T (..7167), w_proj^T (..8191)
__global__ __launch_bounds__(256) void prep_kernel(const float* __restrict__ x, ushort* __restrict__ xb,
    const float* __restrict__ wa, ushort* __restrict__ waT,
    const float* __restrict__ wp, ushort* __restrict__ wpT){
  __shared__ float t[32][33];
  const int bid = blockIdx.x, tid = threadIdx.x;
  if (bid < 4096){
    int i = bid*256 + tid;
    const float4 f = reinterpret_cast<const float4*>(x)[i];
    ushort4 o; o.x=f2bf(f.x); o.y=f2bf(f.y); o.z=f2bf(f.z); o.w=f2bf(f.w);
    reinterpret_cast<ushort4*>(xb)[i] = o;
  } else {
    const float* in; ushort* out; int N, nx, b;
    if (bid < 7168){ b = bid - 4096; in = wa; out = waT; N = N1; nx = N1/32; }
    else           { b = bid - 7168; in = wp; out = wpT; N = EE; nx = EE/32; }
    const int n0 = (b % nx)*32, k0 = (b / nx)*32;
    const int tx = tid & 31, ty = tid >> 5;
    for (int r = ty; r < 32; r += 8)
      t[r][tx] = in[(size_t)(k0+r)*N + n0 + tx];
    __syncthreads();
    for (int r = ty; r < 32; r += 8)
      out[(size_t)(n0+r)*EE + k0 + tx] = f2bf(t[tx][r]);
  }
}

// ---- bf16 GEMM (m97 structure): C = A[M,K]*Bt[N,K]^T + bias.
// MODE 0: scatter to Q[B,H,S,64], K[B,H,S,64], V^T[B,H,64,S] (bf16)
// MODE 1: fp32 row-major out
template<int MODE>
__global__ __launch_bounds__(256) void gemm_nt(const ushort* __restrict__ A,
    const ushort* __restrict__ Bt, const float* __restrict__ bias,
    ushort* __restrict__ q_, ushort* __restrict__ k_, ushort* __restrict__ v_,
    float* __restrict__ of, int M, int N, int K){
  __shared__ ushort As[128*32];
  __shared__ ushort Bs[128*32];
  const int tid = threadIdx.x;
  const int lane = tid & 63, w = tid >> 6;
  // bijective XCD swizzle (nwg % 8 == 0 for both launches: 768, 256)
  const int nx = gridDim.x;
  const int nwg = nx * gridDim.y;
  const int flat = blockIdx.y*nx + blockIdx.x;
  const int sw = (flat & 7)*(nwg >> 3) + (flat >> 3);
  const int m0 = (sw / nx)*128, n0 = (sw % nx)*128;
  const int wm = (w >> 1)*64, wn = (w & 1)*64;
  const int lr = lane & 15, lk = (lane >> 4)*8;
  const int c0 = w*2;
  const int srow = lane >> 2;
  const int scb  = (lane & 3)*8;
  const ushort* Ag0 = A  + (size_t)(m0 + c0*16      + srow)*K + scb;
  const ushort* Ag1 = A  + (size_t)(m0 + c0*16 + 16 + srow)*K + scb;
  const ushort* Bg0 = Bt + (size_t)(n0 + c0*16      + srow)*K + scb;
  const ushort* Bg1 = Bt + (size_t)(n0 + c0*16 + 16 + srow)*K + scb;
  ushort* Al0 = &As[(c0*16)*32];
  ushort* Al1 = &As[(c0*16 + 16)*32];
  ushort* Bl0 = &Bs[(c0*16)*32];
  ushort* Bl1 = &Bs[(c0*16 + 16)*32];

  f32x4 acc[4][4] = {};
  for (int k0 = 0; k0 < K; k0 += 32){
    gload16(Ag0 + k0, Al0);
    gload16(Ag1 + k0, Al1);
    gload16(Bg0 + k0, Bl0);
    gload16(Bg1 + k0, Bl1);
    __syncthreads();
    bf16x8 af[4], bfr[4];
    #pragma unroll
    for (int m = 0; m < 4; ++m)
      af[m] = *reinterpret_cast<bf16x8*>(&As[(wm + m*16 + lr)*32 + lk]);
    #pragma unroll
    for (int n = 0; n < 4; ++n)
      bfr[n] = *reinterpret_cast<bf16x8*>(&Bs[(wn + n*16 + lr)*32 + lk]);
    __builtin_amdgcn_s_setprio(1);
    #pragma unroll
    for (int m = 0; m < 4; ++m)
      #pragma unroll
      for (int n = 0; n < 4; ++n)
        acc[m][n] = __builtin_amdgcn_mfma_f32_16x16x32_bf16(af[m], bfr[n], acc[m][n], 0, 0, 0);
    __builtin_amdgcn_s_setprio(0);
    __syncthreads();
  }
  #pragma unroll
  for (int m = 0; m < 4; ++m){
    #pragma unroll
    for (int n = 0; n < 4; ++n){
      int col = n0 + wn + n*16 + lr;
      float bv = bias[col];
      #pragma unroll
      for (int r = 0; r < 4; ++r){
        int row = m0 + wm + m*16 + (lane >> 4)*4 + r;
        float v = acc[m][n][r] + bv;
        if (MODE == 1){
          of[(size_t)row*N + col] = v;
        } else {
          int b = row >> 11, s = row & 2047;
          int h = col / 192, t = col - h*192;
          ushort u = f2bf(v);
          size_t bh = (size_t)(b*HH + h);
          if (t < 64)       q_[(bh*SS + s)*DD + t]        = u;
          else if (t < 128) k_[(bh*SS + s)*DD + (t-64)]   = u;
          else              v_[(bh*DD + (t-128))*SS + s]  = u;
        }
      }
    }
  }
}

// ---- causal flash attention, swapped-QK 32x32, dbuf + async staging ----
#define SCL 0.18033688f          /* log2(e)/8 */
#define THRRAW 44.3614f          /* 8 / SCL   */
__global__ __launch_bounds__(256,2) void attn2(const ushort* __restrict__ Qg,
    const ushort* __restrict__ Kg, const ushort* __restrict__ Vg,
    ushort* __restrict__ aout){
  __shared__ __align__(16) ushort Kl[2][64*64];
  __shared__ __align__(16) ushort Vl[2][64*64];
  const int tid = threadIdx.x, lane = tid & 63, w = tid >> 6;
  const int bh = blockIdx.x;
  const int y  = blockIdx.y;
  const int qt = (y < 8) ? 2*y : 31 - 2*y;          // complementary pairing
  const int b = bh >> 4, h = bh & 15;
  const int q0 = qt*128;
  const int ql = lane & 31, g = lane >> 5;
  const int qrow = q0 + w*32 + ql;
  const int qminw = q0 + w*32;
  const int qmaxw = qminw + 31;

  const ushort* Qp = Qg + ((size_t)bh*SS + qrow)*DD;
  bf16x8 qf[4];
  #pragma unroll
  for (int s = 0; s < 4; ++s)
    qf[s] = *(const bf16x8*)(Qp + s*16 + g*8);

  f32x16 ot[2] = {};
  float mr = -1e30f, sr = 0.f;

  const int csr = lane >> 3;
  const int gcb = ((lane & 7) ^ csr)*8;
  const ushort* Kbase = Kg + (size_t)bh*SS*DD;
  const ushort* Vbase = Vg + (size_t)bh*DD*SS;
  const int nkb = (q0 + 128) >> 6;

  auto stage = [&](int k0, int bi){
    #pragma unroll
    for (int i = 0; i < 2; ++i){
      const int c = w*2 + i;
      gload16(Kbase + (size_t)(k0 + c*8 + csr)*DD + gcb, &Kl[bi][(c*8)*64]);
      gload16(Vbase + (size_t)(c*8 + csr)*SS + k0 + gcb, &Vl[bi][(c*8)*64]);
    }
  };

  stage(0, 0);
  int buf = 0;
  for (int kb = 0; kb < nkb; ++kb){
    const int k0 = kb*64;
    __syncthreads();
    if (kb + 1 < nkb) stage(k0 + 64, buf ^ 1);
    if (k0 <= qmaxw){
      const ushort* Kc = &Kl[buf][0];
      const ushort* Vc = &Vl[buf][0];
      const int swq = (ql & 7);
      // S^T = K * Q^T
      f32x16 st0 = {}, st1 = {};
      __builtin_amdgcn_s_setprio(1);
      #pragma unroll
      for (int s = 0; s < 4; ++s){
        bf16x8 kf0 = *(const bf16x8*)&Kc[ ql     *64 + (((2*s + g) ^ swq)*8)];
        bf16x8 kf1 = *(const bf16x8*)&Kc[(32+ql) *64 + (((2*s + g) ^ swq)*8)];
        st0 = __builtin_amdgcn_mfma_f32_32x32x16_bf16(kf0, qf[s], st0, 0, 0, 0);
        st1 = __builtin_amdgcn_mfma_f32_32x32x16_bf16(kf1, qf[s], st1, 0, 0, 0);
      }
      __builtin_amdgcn_s_setprio(0);
      float p[2][16];
      #pragma unroll
      for (int r = 0; r < 16; ++r){ p[0][r] = st0[r]; p[1][r] = st1[r]; }  // raw scores
      if (k0 + 63 > qminw){
        #pragma unroll
        for (int kf = 0; kf < 2; ++kf)
          #pragma unroll
          for (int r = 0; r < 16; ++r){
            int kg = k0 + kf*32 + (r & 3) + 8*(r >> 2) + 4*g;
            p[kf][r] = (kg > qrow) ? -1e30f : p[kf][r];
          }
      }
      // tile row-max: in-register tree + permlane32 half-swap
      float m8[8];
      #pragma unroll
      for (int i = 0; i < 8; ++i)
        m8[i] = fmaxf(fmaxf(p[0][i], p[0][i+8]), fmaxf(p[1][i], p[1][i+8]));
      float tm = fmaxf(fmaxf(fmaxf(m8[0],m8[1]), fmaxf(m8[2],m8[3])),
                       fmaxf(fmaxf(m8[4],m8[5]), fmaxf(m8[6],m8[7])));
      { u32x2 rm = pl32swap(__float_as_uint(tm), __float_as_uint(tm));
        tm = fmaxf(__uint_as_float(rm[0]), __uint_as_float(rm[1])); }
      // defer-max: rescale only if growth exceeds 2^8 headroom
      if (__any(tm > mr + THRRAW)){
        float nm = fmaxf(mr, tm);
        float fac = exp2_fast((mr - nm)*SCL);
        #pragma unroll
        for (int r = 0; r < 16; ++r){ ot[0][r] *= fac; ot[1][r] *= fac; }
        sr *= fac;
        mr = nm;
      }
      const float nms = mr * SCL;
      #pragma unroll
      for (int kf = 0; kf < 2; ++kf)
        #pragma unroll
        for (int r = 0; r < 16; ++r)
          p[kf][r] = exp2_fast(__builtin_fmaf(p[kf][r], SCL, -nms));
      float s8[8];
      #pragma unroll
      for (int i = 0; i < 8; ++i)
        s8[i] = (p[0][i] + p[0][i+8]) + (p[1][i] + p[1][i+8]);
      float ts = ((s8[0]+s8[1]) + (s8[2]+s8[3])) + ((s8[4]+s8[5]) + (s8[6]+s8[7]));
      { u32x2 rs = pl32swap(__float_as_uint(ts), __float_as_uint(ts));
        ts = __uint_as_float(rs[0]) + __uint_as_float(rs[1]); }
      sr += ts;

      // PV: O^T += V^T * P^T; P rebuilt in-register via permlane32_swap.
      // Want pw.u[0] = {l<32: own cvtpk(p0,p1); l>=32: partner cvtpk(p4,p5)}
      //      pw.u[2] = {l<32: partner cvtpk(p0,p1); l>=32: own cvtpk(p4,p5)}
      // => r0 = pl32swap(cvtpk(p0,p1), cvtpk(p4,p5)); pw.u[0]=r0[0], pw.u[2]=r0[1].
      __builtin_amdgcn_s_setprio(1);
      #pragma unroll
      for (int kf = 0; kf < 2; ++kf){
        #pragma unroll
        for (int s2 = 0; s2 < 2; ++s2){
          const int base = s2*8;
          unsigned u0 = cvt_pk(p[kf][base+0], p[kf][base+1]);
          unsigned u1 = cvt_pk(p[kf][base+2], p[kf][base+3]);
          unsigned u2 = cvt_pk(p[kf][base+4], p[kf][base+5]);
          unsigned u3 = cvt_pk(p[kf][base+6], p[kf][base+7]);
          u32x2 r0 = pl32swap(u0, u2);
          u32x2 r1 = pl32swap(u1, u3);
          union { u32x4 u; bf16x8 hv; } pw;
          pw.u[0] = r0[0]; pw.u[1] = r1[0]; pw.u[2] = r0[1]; pw.u[3] = r1[1];
          const int cbv = 4*kf + 2*s2 + g;
          bf16x8 v0f = *(const bf16x8*)&Vc[ ql     *64 + ((cbv ^ swq)*8)];
          bf16x8 v1f = *(const bf16x8*)&Vc[(32+ql) *64 + ((cbv ^ swq)*8)];
          ot[0] = __builtin_amdgcn_mfma_f32_32x32x16_bf16(v0f, pw.hv, ot[0], 0, 0, 0);
          ot[1] = __builtin_amdgcn_mfma_f32_32x32x16_bf16(v1f, pw.hv, ot[1], 0, 0, 0);
        }
      }
      __builtin_amdgcn_s_setprio(0);
    }
    buf ^= 1;
  }
  const float inv = 1.f / sr;
  const size_t obase = ((size_t)b*SS + qrow)*EE + h*DD;
  #pragma unroll
  for (int df = 0; df < 2; ++df){
    #pragma unroll
    for (int t = 0; t < 4; ++t){
      ushort4 o4;
      o4.x = f2bf(ot[df][t*4+0]*inv);
      o4.y = f2bf(ot[df][t*4+1]*inv);
      o4.z = f2bf(ot[df][t*4+2]*inv);
      o4.w = f2bf(ot[df][t*4+3]*inv);
      int d = df*32 + 8*t + 4*g;
      *(ushort4*)&aout[obase + d] = o4;
    }
  }
}

extern "C" void kernel_launch(void* const* d_in, const int* in_sizes, int n_in,
                              void* d_out, int out_size, void* d_ws, size_t ws_size,
                              hipStream_t stream){
  const float* x      = (const float*)d_in[0];
  const float* w_attn = (const float*)d_in[1];
  const float* b_attn = (const float*)d_in[2];
  const float* w_proj = (const float*)d_in[3];
  const float* b_proj = (const float*)d_in[4];
  float* out = (float*)d_out;

  ushort* ws   = (ushort*)d_ws;
  ushort* xb   = ws;                           // [4096,1024] bf16
  ushort* waT  = xb  + (size_t)MM*EE;          // [3072,1024] bf16 (w_attn^T)
  ushort* wpT  = waT + (size_t)N1*EE;          // [1024,1024] bf16 (w_proj^T)
  ushort* qb_  = wpT + (size_t)EE*EE;          // Q  [B,H,S,64]
  ushort* kb_  = qb_ + (size_t)MM*EE;          // K  [B,H,S,64]
  ushort* vTb  = kb_ + (size_t)MM*EE;          // V^T[B,H,64,S]
  ushort* ab   = vTb + (size_t)MM*EE;          // attn out [B,S,E]

  prep_kernel<<<8192, 256, 0, stream>>>(x, xb, w_attn, waT, w_proj, wpT);
  gemm_nt<0><<<dim3(N1/128, MM/128), 256, 0, stream>>>(xb, waT, b_attn, qb_, kb_, vTb, nullptr, MM, N1, EE);
  attn2<<<dim3(BB*HH, SS/128), 256, 0, stream>>>(qb_, kb_, vTb, ab);
  gemm_nt<1><<<dim3(EE/128, MM/128), 256, 0, stream>>>(ab, wpT, b_proj, nullptr, nullptr, nullptr, out, MM, EE, EE);
}